// Round 9
// baseline (60.954 us; speedup 1.0000x reference)
//
#include <hip/hip_runtime.h>

#define NB 16
#define NC 8
#define HW (512*512)
#define NT 16                 // tags 1..16 (tag 0 never participates)
#define LGG 3.0f

#define BLOCKS 2048           // 8 blocks/CU exactly (256 CU)
#define THREADS 256
#define BPSAMP (BLOCKS/NB)    // 128 blocks per sample
#define PXB (HW/BPSAMP)       // 2048 pixels per block
#define PXW (PXB/4)           // 512 pixels per wave
#define NMFMA (PXW/32)        // 16 MFMAs per wave
#define NCOL 10               // D cols: 0..7 ch sums, 8 count, 9 masked count
#define ACCW (NT*NCOL)        // 160 floats per sample

typedef __attribute__((ext_vector_type(8))) short bf16x8;
typedef __attribute__((ext_vector_type(4))) float f32x4;

__device__ __forceinline__ unsigned pk_bf16(float x, float y) {
    unsigned r;
    asm("v_cvt_pk_bf16_f32 %0, %1, %2" : "=v"(r) : "v"(x), "v"(y));
    return r;   // lo = bf16(x), hi = bf16(y), RNE
}

struct Frag { int4 g0, g1, m0, m1; float4 v0, v1; };

__device__ __forceinline__ Frag ld(const int* gkp, const int* mkp,
                                   const float* sp, int off) {
    Frag f;
    f.g0 = *(const int4*)(gkp + off);
    f.g1 = *(const int4*)(gkp + off + 4);
    f.m0 = *(const int4*)(mkp + off);
    f.m1 = *(const int4*)(mkp + off + 4);
    f.v0 = *(const float4*)(sp + off);
    f.v1 = *(const float4*)(sp + off + 4);
    return f;
}

__device__ __forceinline__ unsigned onehot2(int a, int b, int r1) {
    return (a == r1 ? 0x3F80u : 0u) | (b == r1 ? 0x3F800000u : 0u);
}
__device__ __forceinline__ unsigned mask2(int a, int b) {
    return (a ? 0x3F80u : 0u) | (b ? 0x3F800000u : 0u);
}

__device__ __forceinline__ f32x4 step(const Frag& f, int c, int r1, f32x4 acc) {
    union { bf16x8 v; unsigned u[4]; } A, B;
    A.u[0] = onehot2(f.g0.x, f.g0.y, r1);
    A.u[1] = onehot2(f.g0.z, f.g0.w, r1);
    A.u[2] = onehot2(f.g1.x, f.g1.y, r1);
    A.u[3] = onehot2(f.g1.z, f.g1.w, r1);
    const unsigned bs0 = pk_bf16(f.v0.x, f.v0.y), bs1 = pk_bf16(f.v0.z, f.v0.w);
    const unsigned bs2 = pk_bf16(f.v1.x, f.v1.y), bs3 = pk_bf16(f.v1.z, f.v1.w);
    const unsigned bm0 = mask2(f.m0.x, f.m0.y), bm1 = mask2(f.m0.z, f.m0.w);
    const unsigned bm2 = mask2(f.m1.x, f.m1.y), bm3 = mask2(f.m1.z, f.m1.w);
    // per-lane uniform role select (cndmask chains; no control flow)
    B.u[0] = c < 8 ? bs0 : (c == 8 ? 0x3F803F80u : (c == 9 ? bm0 : 0u));
    B.u[1] = c < 8 ? bs1 : (c == 8 ? 0x3F803F80u : (c == 9 ? bm1 : 0u));
    B.u[2] = c < 8 ? bs2 : (c == 8 ? 0x3F803F80u : (c == 9 ? bm2 : 0u));
    B.u[3] = c < 8 ? bs3 : (c == 8 ? 0x3F803F80u : (c == 9 ? bm3 : 0u));
    return __builtin_amdgcn_mfma_f32_16x16x32_bf16(A.v, B.v, acc, 0, 0, 0);
}

__global__ __launch_bounds__(256) void init_ws(float* g_acc) {
    const int i = threadIdx.x;
    #pragma unroll
    for (int k = 0; k < NB*ACCW; k += 256)
        if (k + i < NB*ACCW) g_acc[k + i] = 0.f;
}

// branch-free loads + explicit depth-2 rotating prefetch (fully unrolled ->
// static buffer indices -> registers). launch_bounds(.,1): don't let the
// allocator force a 64-VGPR occupancy target and spill (R2-R4 lesson).
__global__ __launch_bounds__(THREADS, 1) void accum(
    const int* __restrict__ gk, const int* __restrict__ mask,
    const float* __restrict__ sim, float* __restrict__ g_acc)
{
    const int tid  = threadIdx.x;
    const int lane = tid & 63, wid = tid >> 6;
    const int bid  = blockIdx.x;
    const int b    = bid / BPSAMP;          // sample
    const int sb   = bid % BPSAMP;          // block within sample
    const int c    = lane & 15;             // D column role: 0..7 ch, 8 ones, 9 mask
    const int l4   = lane >> 4;             // k-chunk 0..3 (8 pixels each)
    const int p0   = sb * PXB + wid * PXW + l4 * 8;

    const int*   gkp = gk   + (size_t)b * HW + p0;
    const int*   mkp = mask + (size_t)b * HW + p0;
    // clamped channel for c>=8 lanes: same cache lines as the c<8 lanes
    const float* sp  = sim  + ((size_t)b * NC + (c & 7)) * HW + p0;

    __shared__ float lred[4][256];

    f32x4 acc = {0.f, 0.f, 0.f, 0.f};
    const int r1 = c + 1;                   // this lane's one-hot tag

    Frag fr[3];
    fr[0] = ld(gkp, mkp, sp, 0);
    fr[1] = ld(gkp, mkp, sp, 32);
    #pragma unroll
    for (int it = 0; it < NMFMA; ++it) {
        if (it + 2 < NMFMA)
            fr[(it + 2) % 3] = ld(gkp, mkp, sp, (it + 2) * 32);
        acc = step(fr[it % 3], c, r1, acc);
    }

    // D layout: col = lane&15, row = (lane>>4)*4 + reg  (verified R7/R8)
    const int row0 = (lane >> 4) * 4;
    #pragma unroll
    for (int i = 0; i < 4; ++i) lred[wid][(row0 + i) * 16 + c] = acc[i];
    __syncthreads();

    if (tid < NT * NCOL) {                  // 160: r = tag row, cc = column
        const int r = tid / NCOL, cc = tid % NCOL;
        const float s = lred[0][r*16+cc] + lred[1][r*16+cc]
                      + lred[2][r*16+cc] + lred[3][r*16+cc];
        atomicAdd(&g_acc[b * ACCW + tid], s);
    }
}

__global__ __launch_bounds__(256) void finalize(
    const float* __restrict__ g_acc, float* __restrict__ out)
{
    __shared__ float    means[NB][NT][NC];
    __shared__ unsigned pres[NB];
    __shared__ float    sl[NB], sn[NB];
    const int tid = threadIdx.x;

    if (tid < NB) pres[tid] = 0u;
    __syncthreads();

    // one thread per (sample, tag): means + presence
    {
        const int b = tid >> 4, t = tid & 15;
        const float* row = g_acc + b * ACCW + t * NCOL;
        const float cnt = row[8];
        const float mc  = row[9];
        const float inv = 1.f / fmaxf(cnt, 1.f);
        #pragma unroll
        for (int cc = 0; cc < NC; ++cc) means[b][t][cc] = row[cc] * inv;
        if (mc > 0.5f) atomicOr(&pres[b], 1u << (t + 1));
    }
    __syncthreads();

    const int b = tid >> 4, i = tid & 15;          // sample, tag-1
    const unsigned pr = pres[b];                    // bits 1..16
    float loss = 0.f, nv = 0.f;
    if ((pr >> (i + 1)) & 1u) {
        #pragma unroll
        for (int j = 0; j < NT; ++j) {
            if (j != i && ((pr >> (j + 1)) & 1u)) {
                float d2 = 0.f;
                #pragma unroll
                for (int cc = 0; cc < NC; ++cc) {
                    const float d = means[b][i][cc] - means[b][j][cc];
                    d2 += d * d;
                }
                const float dist = sqrtf(d2 + 1e-12f);
                const float r = fmaxf(LGG - dist, 0.f);
                loss += logf(r * r + 1.f);
                nv += 1.f;
            }
        }
    }
    #pragma unroll
    for (int o = 8; o; o >>= 1) { loss += __shfl_xor(loss, o); nv += __shfl_xor(nv, o); }
    if (i == 0) {
        const float v = (__popc(pr) >= 2) ? 1.f : 0.f;
        sl[b] = v * (loss / fmaxf(nv, 1.f));
        sn[b] = v;
    }
    __syncthreads();
    if (tid == 0) {
        float tl = 0.f, tv = 0.f;
        for (int bb = 0; bb < NB; ++bb) { tl += sl[bb]; tv += sn[bb]; }
        out[0] = (tv > 0.f) ? tl / tv : 0.f;
    }
}

extern "C" void kernel_launch(void* const* d_in, const int* in_sizes, int n_in,
                              void* d_out, int out_size, void* d_ws, size_t ws_size,
                              hipStream_t stream) {
    const int*   gk   = (const int*)d_in[0];
    const int*   mask = (const int*)d_in[1];
    const float* sim  = (const float*)d_in[2];
    float* out   = (float*)d_out;
    float* g_acc = (float*)d_ws;      // NB*160 floats

    init_ws<<<1, 256, 0, stream>>>(g_acc);
    accum<<<BLOCKS, THREADS, 0, stream>>>(gk, mask, sim, g_acc);
    finalize<<<1, 256, 0, stream>>>(g_acc, out);
}

// Round 10
// 54.536 us; speedup vs baseline: 1.1177x; 1.1177x over previous
//
#include <hip/hip_runtime.h>

#define NB 16
#define NC 8
#define HW (512*512)
#define NT 16                 // tags 1..16 (tag 0 never participates)
#define LGG 3.0f

#define BLOCKS 2048           // 8 blocks/CU exactly (256 CU)
#define THREADS 256
#define BPSAMP (BLOCKS/NB)    // 128 blocks per sample
#define PXB (HW/BPSAMP)       // 2048 pixels per block
#define PXW (PXB/4)           // 512 pixels per wave
#define NMFMA (PXW/32)        // 16 MFMAs per wave
#define NCOL 10               // D cols: 0..7 ch sums, 8 count, 9 masked count
#define ACCW (NT*NCOL)        // 160 floats per sample

typedef __attribute__((ext_vector_type(8))) short bf16x8;
typedef __attribute__((ext_vector_type(4))) float f32x4;

__device__ __forceinline__ unsigned pk_bf16(float x, float y) {
    unsigned r;
    asm("v_cvt_pk_bf16_f32 %0, %1, %2" : "=v"(r) : "v"(x), "v"(y));
    return r;   // lo = bf16(x), hi = bf16(y), RNE
}

struct Frag { int4 g0, g1, m0, m1; float4 v0, v1; };

// exec-masked loads: only the lanes that consume a stream fetch it
// (R9 lesson: all-lane loads double L1 return traffic and regressed).
__device__ __forceinline__ Frag ldm(const int* gkp, const int* mkp,
                                    const float* sp, int off, int c) {
    Frag f;
    f.g0 = *(const int4*)(gkp + off);
    f.g1 = *(const int4*)(gkp + off + 4);
    if (c < 8) {
        f.v0 = *(const float4*)(sp + off);
        f.v1 = *(const float4*)(sp + off + 4);
    }
    if (c == 9) {
        f.m0 = *(const int4*)(mkp + off);
        f.m1 = *(const int4*)(mkp + off + 4);
    }
    return f;
}

__device__ __forceinline__ unsigned onehot2(int a, int b, int r1) {
    return (a == r1 ? 0x3F80u : 0u) | (b == r1 ? 0x3F800000u : 0u);
}
__device__ __forceinline__ unsigned mask2(int a, int b) {
    return (a ? 0x3F80u : 0u) | (b ? 0x3F800000u : 0u);
}

__device__ __forceinline__ f32x4 step(const Frag& f, int c, int r1, f32x4 acc) {
    union { bf16x8 v; unsigned u[4]; } A, B;
    A.u[0] = onehot2(f.g0.x, f.g0.y, r1);
    A.u[1] = onehot2(f.g0.z, f.g0.w, r1);
    A.u[2] = onehot2(f.g1.x, f.g1.y, r1);
    A.u[3] = onehot2(f.g1.z, f.g1.w, r1);
    const unsigned bs0 = pk_bf16(f.v0.x, f.v0.y), bs1 = pk_bf16(f.v0.z, f.v0.w);
    const unsigned bs2 = pk_bf16(f.v1.x, f.v1.y), bs3 = pk_bf16(f.v1.z, f.v1.w);
    const unsigned bm0 = mask2(f.m0.x, f.m0.y), bm1 = mask2(f.m0.z, f.m0.w);
    const unsigned bm2 = mask2(f.m1.x, f.m1.y), bm3 = mask2(f.m1.z, f.m1.w);
    B.u[0] = c < 8 ? bs0 : (c == 8 ? 0x3F803F80u : (c == 9 ? bm0 : 0u));
    B.u[1] = c < 8 ? bs1 : (c == 8 ? 0x3F803F80u : (c == 9 ? bm1 : 0u));
    B.u[2] = c < 8 ? bs2 : (c == 8 ? 0x3F803F80u : (c == 9 ? bm2 : 0u));
    B.u[3] = c < 8 ? bs3 : (c == 8 ? 0x3F803F80u : (c == 9 ? bm3 : 0u));
    return __builtin_amdgcn_mfma_f32_16x16x32_bf16(A.v, B.v, acc, 0, 0, 0);
}

__global__ __launch_bounds__(256) void init_ws(float* g_acc) {
    const int i = threadIdx.x;
    #pragma unroll
    for (int k = 0; k < NB*ACCW; k += 256)
        if (k + i < NB*ACCW) g_acc[k + i] = 0.f;
}

// R8 structure + depth-1 double-buffered prefetch (the ONLY change vs R8).
__global__ __launch_bounds__(THREADS) void accum(
    const int* __restrict__ gk, const int* __restrict__ mask,
    const float* __restrict__ sim, float* __restrict__ g_acc)
{
    const int tid  = threadIdx.x;
    const int lane = tid & 63, wid = tid >> 6;
    const int bid  = blockIdx.x;
    const int b    = bid / BPSAMP;          // sample
    const int sb   = bid % BPSAMP;          // block within sample
    const int c    = lane & 15;             // D column role: 0..7 ch, 8 ones, 9 mask
    const int l4   = lane >> 4;             // k-chunk 0..3 (8 pixels each)
    const int p0   = sb * PXB + wid * PXW + l4 * 8;

    const int*   gkp = gk   + (size_t)b * HW + p0;
    const int*   mkp = mask + (size_t)b * HW + p0;
    const float* sp  = sim  + ((size_t)b * NC + (c & 7)) * HW + p0;

    __shared__ float lred[4][256];

    f32x4 acc = {0.f, 0.f, 0.f, 0.f};
    const int r1 = c + 1;                   // this lane's one-hot tag

    Frag cur = ldm(gkp, mkp, sp, 0, c);
    #pragma unroll
    for (int it = 0; it < NMFMA; ++it) {
        Frag nxt;
        if (it + 1 < NMFMA) nxt = ldm(gkp, mkp, sp, (it + 1) * 32, c);
        acc = step(cur, c, r1, acc);
        cur = nxt;
    }

    // D layout: col = lane&15, row = (lane>>4)*4 + reg  (verified R7/R8)
    const int row0 = (lane >> 4) * 4;
    #pragma unroll
    for (int i = 0; i < 4; ++i) lred[wid][(row0 + i) * 16 + c] = acc[i];
    __syncthreads();

    if (tid < NT * NCOL) {                  // 160: r = tag row, cc = column
        const int r = tid / NCOL, cc = tid % NCOL;
        const float s = lred[0][r*16+cc] + lred[1][r*16+cc]
                      + lred[2][r*16+cc] + lred[3][r*16+cc];
        atomicAdd(&g_acc[b * ACCW + tid], s);
    }
}

__global__ __launch_bounds__(256) void finalize(
    const float* __restrict__ g_acc, float* __restrict__ out)
{
    __shared__ float    means[NB][NT][NC];
    __shared__ unsigned pres[NB];
    __shared__ float    sl[NB], sn[NB];
    const int tid = threadIdx.x;

    if (tid < NB) pres[tid] = 0u;
    __syncthreads();

    // one thread per (sample, tag): means + presence
    {
        const int b = tid >> 4, t = tid & 15;
        const float* row = g_acc + b * ACCW + t * NCOL;
        const float cnt = row[8];
        const float mc  = row[9];
        const float inv = 1.f / fmaxf(cnt, 1.f);
        #pragma unroll
        for (int cc = 0; cc < NC; ++cc) means[b][t][cc] = row[cc] * inv;
        if (mc > 0.5f) atomicOr(&pres[b], 1u << (t + 1));
    }
    __syncthreads();

    const int b = tid >> 4, i = tid & 15;          // sample, tag-1
    const unsigned pr = pres[b];                    // bits 1..16
    float loss = 0.f, nv = 0.f;
    if ((pr >> (i + 1)) & 1u) {
        #pragma unroll
        for (int j = 0; j < NT; ++j) {
            if (j != i && ((pr >> (j + 1)) & 1u)) {
                float d2 = 0.f;
                #pragma unroll
                for (int cc = 0; cc < NC; ++cc) {
                    const float d = means[b][i][cc] - means[b][j][cc];
                    d2 += d * d;
                }
                const float dist = sqrtf(d2 + 1e-12f);
                const float r = fmaxf(LGG - dist, 0.f);
                loss += logf(r * r + 1.f);
                nv += 1.f;
            }
        }
    }
    #pragma unroll
    for (int o = 8; o; o >>= 1) { loss += __shfl_xor(loss, o); nv += __shfl_xor(nv, o); }
    if (i == 0) {
        const float v = (__popc(pr) >= 2) ? 1.f : 0.f;
        sl[b] = v * (loss / fmaxf(nv, 1.f));
        sn[b] = v;
    }
    __syncthreads();
    if (tid == 0) {
        float tl = 0.f, tv = 0.f;
        for (int bb = 0; bb < NB; ++bb) { tl += sl[bb]; tv += sn[bb]; }
        out[0] = (tv > 0.f) ? tl / tv : 0.f;
    }
}

extern "C" void kernel_launch(void* const* d_in, const int* in_sizes, int n_in,
                              void* d_out, int out_size, void* d_ws, size_t ws_size,
                              hipStream_t stream) {
    const int*   gk   = (const int*)d_in[0];
    const int*   mask = (const int*)d_in[1];
    const float* sim  = (const float*)d_in[2];
    float* out   = (float*)d_out;
    float* g_acc = (float*)d_ws;      // NB*160 floats

    init_ws<<<1, 256, 0, stream>>>(g_acc);
    accum<<<BLOCKS, THREADS, 0, stream>>>(gk, mask, sim, g_acc);
    finalize<<<1, 256, 0, stream>>>(g_acc, out);
}

// Round 11
// 44.991 us; speedup vs baseline: 1.3548x; 1.2122x over previous
//
#include <hip/hip_runtime.h>

#define NB 16
#define NC 8
#define HW (512*512)
#define NT 16                 // tags 1..16 (tag 0 never participates)
#define LGG 3.0f

#define BLOCKS 2048           // 8 blocks/CU exactly (256 CU)
#define THREADS 256
#define BPSAMP (BLOCKS/NB)    // 128 blocks per sample
#define PXB (HW/BPSAMP)       // 2048 pixels per block
#define TILE 512              // pixels staged per LDS tile
#define NTILES (PXB/TILE)     // 4
#define JITERS (TILE/128)     // 4 MFMA-iters per wave per tile (128 px/wave)
#define NCHUNK (2 + 2*NC)     // 18 x 1KB global_load_lds chunks per tile
#define NCOL 10               // D cols: 0..7 ch sums, 8 count, 9 masked count
#define ACCW (NT*NCOL)        // 160 floats per sample

#define SIM_LDS 2048          // byte offset of sim planes in ldsbuf
#define PLANE_STRIDE 2064     // 2048 data + 16 pad (4-way sim-read conflict, ok)
#define LDS_BYTES (SIM_LDS + NC*PLANE_STRIDE)   // 18560 -> 8 blocks/CU

typedef __attribute__((ext_vector_type(8))) short bf16x8;
typedef __attribute__((ext_vector_type(4))) float f32x4;

__device__ __forceinline__ unsigned pk_bf16(float x, float y) {
    unsigned r;
    asm("v_cvt_pk_bf16_f32 %0, %1, %2" : "=v"(r) : "v"(x), "v"(y));
    return r;   // lo = bf16(x), hi = bf16(y), RNE
}

__device__ __forceinline__ unsigned onehot2(int a, int b, int r1) {
    return (a == r1 ? 0x3F80u : 0u) | (b == r1 ? 0x3F800000u : 0u);
}
__device__ __forceinline__ unsigned mask2(int a, int b) {
    return (a ? 0x3F80u : 0u) | (b ? 0x3F800000u : 0u);
}

// async global->LDS, 16B per lane: dest = (wave-uniform lds) + lane*16,
// src = per-lane global address. Size must be a literal (16).
__device__ __forceinline__ void gload_lds16(const void* g, void* lds) {
    __builtin_amdgcn_global_load_lds(
        (const __attribute__((address_space(1))) void*)g,
        (__attribute__((address_space(3))) void*)lds, 16, 0, 0);
}

__global__ __launch_bounds__(256) void init_ws(float* g_acc) {
    const int i = threadIdx.x;
    #pragma unroll
    for (int k = 0; k < NB*ACCW; k += 256)
        if (k + i < NB*ACCW) g_acc[k + i] = 0.f;
}

// Copy-shaped staging (global_load_lds, contiguous 1KB/wave-instr) + LDS consume.
__global__ __launch_bounds__(THREADS) void accum(
    const int* __restrict__ gk, const int* __restrict__ mask,
    const float* __restrict__ sim, float* __restrict__ g_acc)
{
    const int tid  = threadIdx.x;
    const int lane = tid & 63, wid = tid >> 6;
    const int bid  = blockIdx.x;
    const int b    = bid / BPSAMP;          // sample
    const int sb   = bid % BPSAMP;          // block within sample
    const int c    = lane & 15;             // D column role: 0..7 ch, 8 ones, 9 mask
    const int l4   = lane >> 4;             // k-chunk 0..3 (8 pixels each)
    const int base = sb * PXB;

    __shared__ __align__(16) char ldsbuf[LDS_BYTES];

    const int*   gkS = gk   + (size_t)b * HW + base;
    const int*   mkS = mask + (size_t)b * HW + base;
    const float* smS = sim  + (size_t)b * NC * HW + base;   // plane p at +p*HW

    f32x4 acc = {0.f, 0.f, 0.f, 0.f};
    const int r1 = c + 1;                   // this lane's one-hot tag
    const int simoff = SIM_LDS + (c & 7) * PLANE_STRIDE;    // clamped for c>=8

    for (int t = 0; t < NTILES; ++t) {
        const int t0 = t * TILE;
        // ---- stage tile t: wave wid issues chunks wid, wid+4, ... ----
        #pragma unroll
        for (int k = 0; k < 5; ++k) {
            const int idx = wid + 4 * k;
            if (idx < NCHUNK) {
                const void* src;
                int dst;
                if (idx < 2) {              // gk halves
                    src = gkS + t0 + idx * 256 + lane * 4;
                    dst = idx * 1024;
                } else {                    // sim plane p, half h
                    const int p = (idx - 2) >> 1, h = (idx - 2) & 1;
                    src = smS + (size_t)p * HW + t0 + h * 256 + lane * 4;
                    dst = SIM_LDS + p * PLANE_STRIDE + h * 1024;
                }
                gload_lds16(src, ldsbuf + dst);
            }
        }
        // mask prefetch for j=0 (c==9 lanes only; thin 16MB stream)
        int4 mc0, mc1;
        if (c == 9) {
            const int* mp = mkS + t0 + wid * 128 + l4 * 8;
            mc0 = *(const int4*)mp; mc1 = *(const int4*)(mp + 4);
        }
        __syncthreads();                    // drains vmcnt -> LDS + mask regs valid

        // ---- consume tile t from LDS ----
        #pragma unroll
        for (int j = 0; j < JITERS; ++j) {
            int4 mn0, mn1;
            if (j + 1 < JITERS && c == 9) { // depth-1 mask prefetch
                const int* mp = mkS + t0 + wid * 128 + (j + 1) * 32 + l4 * 8;
                mn0 = *(const int4*)mp; mn1 = *(const int4*)(mp + 4);
            }
            const int px = wid * 128 + j * 32 + l4 * 8;     // 8 px per lane
            const int4 g0 = *(const int4*)(ldsbuf + px * 4);
            const int4 g1 = *(const int4*)(ldsbuf + px * 4 + 16);
            const float4 v0 = *(const float4*)(ldsbuf + simoff + px * 4);
            const float4 v1 = *(const float4*)(ldsbuf + simoff + px * 4 + 16);

            union { bf16x8 v; unsigned u[4]; } A, B;
            A.u[0] = onehot2(g0.x, g0.y, r1);
            A.u[1] = onehot2(g0.z, g0.w, r1);
            A.u[2] = onehot2(g1.x, g1.y, r1);
            A.u[3] = onehot2(g1.z, g1.w, r1);
            const unsigned bs0 = pk_bf16(v0.x, v0.y), bs1 = pk_bf16(v0.z, v0.w);
            const unsigned bs2 = pk_bf16(v1.x, v1.y), bs3 = pk_bf16(v1.z, v1.w);
            const unsigned bm0 = mask2(mc0.x, mc0.y), bm1 = mask2(mc0.z, mc0.w);
            const unsigned bm2 = mask2(mc1.x, mc1.y), bm3 = mask2(mc1.z, mc1.w);
            B.u[0] = c < 8 ? bs0 : (c == 8 ? 0x3F803F80u : (c == 9 ? bm0 : 0u));
            B.u[1] = c < 8 ? bs1 : (c == 8 ? 0x3F803F80u : (c == 9 ? bm1 : 0u));
            B.u[2] = c < 8 ? bs2 : (c == 8 ? 0x3F803F80u : (c == 9 ? bm2 : 0u));
            B.u[3] = c < 8 ? bs3 : (c == 8 ? 0x3F803F80u : (c == 9 ? bm3 : 0u));

            acc = __builtin_amdgcn_mfma_f32_16x16x32_bf16(A.v, B.v, acc, 0, 0, 0);
            mc0 = mn0; mc1 = mn1;
        }
        __syncthreads();                    // all reads done before next overwrite
    }

    // ---- tail: overlay reduction scratch on the staging buffer ----
    float* lred = (float*)ldsbuf;           // 4 KB of 18.5 KB, post-barrier safe
    const int row0 = l4 * 4;                // D: col = lane&15, row = l4*4 + reg
    #pragma unroll
    for (int i = 0; i < 4; ++i) lred[wid * 256 + (row0 + i) * 16 + c] = acc[i];
    __syncthreads();

    if (tid < NT * NCOL) {                  // 160: r = tag row, cc = column
        const int r = tid / NCOL, cc = tid % NCOL;
        const float s = lred[0*256 + r*16 + cc] + lred[1*256 + r*16 + cc]
                      + lred[2*256 + r*16 + cc] + lred[3*256 + r*16 + cc];
        atomicAdd(&g_acc[b * ACCW + tid], s);
    }
}

__global__ __launch_bounds__(256) void finalize(
    const float* __restrict__ g_acc, float* __restrict__ out)
{
    __shared__ float    means[NB][NT][NC];
    __shared__ unsigned pres[NB];
    __shared__ float    sl[NB], sn[NB];
    const int tid = threadIdx.x;

    if (tid < NB) pres[tid] = 0u;
    __syncthreads();

    {
        const int b = tid >> 4, t = tid & 15;
        const float* row = g_acc + b * ACCW + t * NCOL;
        const float cnt = row[8];
        const float mc  = row[9];
        const float inv = 1.f / fmaxf(cnt, 1.f);
        #pragma unroll
        for (int cc = 0; cc < NC; ++cc) means[b][t][cc] = row[cc] * inv;
        if (mc > 0.5f) atomicOr(&pres[b], 1u << (t + 1));
    }
    __syncthreads();

    const int b = tid >> 4, i = tid & 15;          // sample, tag-1
    const unsigned pr = pres[b];                    // bits 1..16
    float loss = 0.f, nv = 0.f;
    if ((pr >> (i + 1)) & 1u) {
        #pragma unroll
        for (int j = 0; j < NT; ++j) {
            if (j != i && ((pr >> (j + 1)) & 1u)) {
                float d2 = 0.f;
                #pragma unroll
                for (int cc = 0; cc < NC; ++cc) {
                    const float d = means[b][i][cc] - means[b][j][cc];
                    d2 += d * d;
                }
                const float dist = sqrtf(d2 + 1e-12f);
                const float r = fmaxf(LGG - dist, 0.f);
                loss += logf(r * r + 1.f);
                nv += 1.f;
            }
        }
    }
    #pragma unroll
    for (int o = 8; o; o >>= 1) { loss += __shfl_xor(loss, o); nv += __shfl_xor(nv, o); }
    if (i == 0) {
        const float v = (__popc(pr) >= 2) ? 1.f : 0.f;
        sl[b] = v * (loss / fmaxf(nv, 1.f));
        sn[b] = v;
    }
    __syncthreads();
    if (tid == 0) {
        float tl = 0.f, tv = 0.f;
        for (int bb = 0; bb < NB; ++bb) { tl += sl[bb]; tv += sn[bb]; }
        out[0] = (tv > 0.f) ? tl / tv : 0.f;
    }
}

extern "C" void kernel_launch(void* const* d_in, const int* in_sizes, int n_in,
                              void* d_out, int out_size, void* d_ws, size_t ws_size,
                              hipStream_t stream) {
    const int*   gk   = (const int*)d_in[0];
    const int*   mask = (const int*)d_in[1];
    const float* sim  = (const float*)d_in[2];
    float* out   = (float*)d_out;
    float* g_acc = (float*)d_ws;      // NB*160 floats

    init_ws<<<1, 256, 0, stream>>>(g_acc);
    accum<<<BLOCKS, THREADS, 0, stream>>>(gk, mask, sim, g_acc);
    finalize<<<1, 256, 0, stream>>>(g_acc, out);
}

// Round 12
// 44.703 us; speedup vs baseline: 1.3635x; 1.0064x over previous
//
#include <hip/hip_runtime.h>

#define NB 16
#define NC 8
#define HW (512*512)
#define NT 16                 // tags 1..16 (tag 0 never participates)
#define LGG 3.0f

#define BLOCKS 1024           // 4 blocks/CU exactly (LDS-bound), all co-resident
#define THREADS 256
#define BPSAMP (BLOCKS/NB)    // 64 blocks per sample
#define PXB (HW/BPSAMP)       // 4096 pixels per block
#define TILE 512              // pixels per staged tile
#define NTILES (PXB/TILE)     // 8
#define JITERS 4              // 128 px per wave per j-iter
#define NCOL 10               // D cols: 0..7 ch sums, 8 count, 9 masked count
#define ACCW (NT*NCOL)        // 160 floats per sample

// double-buffered tile: [GK 2KB][MASK 2KB][SIM 8x2KB] = 20480 B per buffer
#define GK_OFF  0
#define MK_OFF  2048
#define SIM_OFF 4096
#define BUF_BYTES 20480
#define LDS_BYTES (2*BUF_BYTES)     // 40960 -> exactly 4 blocks/CU

typedef __attribute__((ext_vector_type(8))) short bf16x8;
typedef __attribute__((ext_vector_type(4))) float f32x4;

__device__ __forceinline__ unsigned pk_bf16(float x, float y) {
    unsigned r;
    asm("v_cvt_pk_bf16_f32 %0, %1, %2" : "=v"(r) : "v"(x), "v"(y));
    return r;   // lo = bf16(x), hi = bf16(y), RNE
}
__device__ __forceinline__ unsigned onehot2(int a, int b, int r1) {
    return (a == r1 ? 0x3F80u : 0u) | (b == r1 ? 0x3F800000u : 0u);
}
__device__ __forceinline__ unsigned mask2(int a, int b) {
    return (a ? 0x3F80u : 0u) | (b ? 0x3F800000u : 0u);
}
__device__ __forceinline__ void gload_lds16(const void* g, void* lds) {
    __builtin_amdgcn_global_load_lds(
        (const __attribute__((address_space(1))) void*)g,
        (__attribute__((address_space(3))) void*)lds, 16, 0, 0);
}

// stage one 512-px tile: 20 x 1KB chunks, wave w takes idx = w, w+4, ... (5 each).
// sim plane p is rotated by 16*p bytes within its 2KB (pre-swizzled GLOBAL src,
// linear LDS dest -- m173 pattern) to break the 2KB plane-stride bank conflict.
__device__ __forceinline__ void stage(const char* gkB, const char* mkB,
                                      const char* smB, char* buf,
                                      int t0b, int wid, int lane) {
    #pragma unroll
    for (int k = 0; k < 5; ++k) {
        const int idx = wid + 4 * k;
        const char* src; int dst;
        if (idx < 2) {
            src = gkB + t0b + idx * 1024 + lane * 16;
            dst = GK_OFF + idx * 1024 + lane * 16;
        } else if (idx < 4) {
            src = mkB + t0b + (idx - 2) * 1024 + lane * 16;
            dst = MK_OFF + (idx - 2) * 1024 + lane * 16;
        } else {
            const int s = idx - 4, p = s >> 1, h = s & 1;
            const int local = h * 1024 + lane * 16;
            const int goff = (local - 16 * p) & 2047;     // inverse rotation
            src = smB + (size_t)p * (HW * 4) + t0b + goff;
            dst = SIM_OFF + p * 2048 + local;
        }
        gload_lds16(src, buf + dst);
    }
}

__global__ __launch_bounds__(256) void init_ws(float* g_acc) {
    const int i = threadIdx.x;
    #pragma unroll
    for (int k = 0; k < NB*ACCW; k += 256)
        if (k + i < NB*ACCW) g_acc[k + i] = 0.f;
}

__global__ __launch_bounds__(THREADS) void accum(
    const int* __restrict__ gk, const int* __restrict__ mask,
    const float* __restrict__ sim, float* __restrict__ g_acc)
{
    const int tid  = threadIdx.x;
    const int lane = tid & 63, wid = tid >> 6;
    const int bid  = blockIdx.x;
    const int b    = bid / BPSAMP;          // sample
    const int sb   = bid % BPSAMP;          // block within sample
    const int c    = lane & 15;             // D column role: 0..7 ch, 8 ones, 9 mask
    const int l4   = lane >> 4;             // k-chunk 0..3 (8 px each)
    const int base = sb * PXB;

    __shared__ __align__(16) char lds[LDS_BYTES];

    const char* gkB = (const char*)(gk   + (size_t)b * HW + base);
    const char* mkB = (const char*)(mask + (size_t)b * HW + base);
    const char* smB = (const char*)(sim  + (size_t)b * NC * HW + base);

    f32x4 acc = {0.f, 0.f, 0.f, 0.f};
    const int r1 = c + 1;
    const int pl = c & 7;                   // sim plane (c<8 lanes)
    const int rot = 16 * pl;

    stage(gkB, mkB, smB, lds, 0, wid, lane);            // tile 0 -> buf 0

    #pragma unroll 1
    for (int t = 0; t < NTILES; ++t) {
        char* cur = lds + (t & 1) * BUF_BYTES;
        if (t + 1 < NTILES) {
            stage(gkB, mkB, smB, lds + ((t + 1) & 1) * BUF_BYTES,
                  (t + 1) * (TILE * 4), wid, lane);
            asm volatile("s_waitcnt vmcnt(5)" ::: "memory");  // tile t drained;
        } else {                                              // t+1's 5 in flight
            asm volatile("s_waitcnt vmcnt(0)" ::: "memory");
        }
        __builtin_amdgcn_sched_barrier(0);
        __builtin_amdgcn_s_barrier();       // all waves' tile-t chunks visible

        #pragma unroll
        for (int j = 0; j < JITERS; ++j) {
            const int o = (wid * 128 + j * 32 + l4 * 8) * 4;  // byte off, <2048
            const int4 g0 = *(const int4*)(cur + GK_OFF + o);
            const int4 g1 = *(const int4*)(cur + GK_OFF + o + 16);
            float4 v0 = {0,0,0,0}, v1 = {0,0,0,0};
            if (c < 8) {
                const char* sp = cur + SIM_OFF + pl * 2048;
                v0 = *(const float4*)(sp + ((o + rot) & 2047));
                v1 = *(const float4*)(sp + ((o + 16 + rot) & 2047));
            }
            int4 m0 = {0,0,0,0}, m1 = {0,0,0,0};
            if (c == 9) {
                m0 = *(const int4*)(cur + MK_OFF + o);
                m1 = *(const int4*)(cur + MK_OFF + o + 16);
            }

            union { bf16x8 v; unsigned u[4]; } A, B;
            A.u[0] = onehot2(g0.x, g0.y, r1);
            A.u[1] = onehot2(g0.z, g0.w, r1);
            A.u[2] = onehot2(g1.x, g1.y, r1);
            A.u[3] = onehot2(g1.z, g1.w, r1);
            const unsigned bs0 = pk_bf16(v0.x, v0.y), bs1 = pk_bf16(v0.z, v0.w);
            const unsigned bs2 = pk_bf16(v1.x, v1.y), bs3 = pk_bf16(v1.z, v1.w);
            const unsigned bm0 = mask2(m0.x, m0.y), bm1 = mask2(m0.z, m0.w);
            const unsigned bm2 = mask2(m1.x, m1.y), bm3 = mask2(m1.z, m1.w);
            B.u[0] = c < 8 ? bs0 : (c == 8 ? 0x3F803F80u : (c == 9 ? bm0 : 0u));
            B.u[1] = c < 8 ? bs1 : (c == 8 ? 0x3F803F80u : (c == 9 ? bm1 : 0u));
            B.u[2] = c < 8 ? bs2 : (c == 8 ? 0x3F803F80u : (c == 9 ? bm2 : 0u));
            B.u[3] = c < 8 ? bs3 : (c == 8 ? 0x3F803F80u : (c == 9 ? bm3 : 0u));

            acc = __builtin_amdgcn_mfma_f32_16x16x32_bf16(A.v, B.v, acc, 0, 0, 0);
        }
        __builtin_amdgcn_s_barrier();       // reads done before parity overwrite
    }

    // ---- tail: overlay reduction scratch on buf0 (post-barrier safe) ----
    float* lred = (float*)lds;
    const int row0 = l4 * 4;                // D: col = lane&15, row = l4*4 + reg
    #pragma unroll
    for (int i = 0; i < 4; ++i) lred[wid * 256 + (row0 + i) * 16 + c] = acc[i];
    __syncthreads();

    if (tid < NT * NCOL) {                  // 160: r = tag row, cc = column
        const int r = tid / NCOL, cc = tid % NCOL;
        const float s = lred[0*256 + r*16 + cc] + lred[1*256 + r*16 + cc]
                      + lred[2*256 + r*16 + cc] + lred[3*256 + r*16 + cc];
        atomicAdd(&g_acc[b * ACCW + tid], s);
    }
}

__global__ __launch_bounds__(256) void finalize(
    const float* __restrict__ g_acc, float* __restrict__ out)
{
    __shared__ float    means[NB][NT][NC];
    __shared__ unsigned pres[NB];
    __shared__ float    sl[NB], sn[NB];
    const int tid = threadIdx.x;

    if (tid < NB) pres[tid] = 0u;
    __syncthreads();

    {
        const int b = tid >> 4, t = tid & 15;
        const float* row = g_acc + b * ACCW + t * NCOL;
        const float cnt = row[8];
        const float mc  = row[9];
        const float inv = 1.f / fmaxf(cnt, 1.f);
        #pragma unroll
        for (int cc = 0; cc < NC; ++cc) means[b][t][cc] = row[cc] * inv;
        if (mc > 0.5f) atomicOr(&pres[b], 1u << (t + 1));
    }
    __syncthreads();

    const int b = tid >> 4, i = tid & 15;          // sample, tag-1
    const unsigned pr = pres[b];                    // bits 1..16
    float loss = 0.f, nv = 0.f;
    if ((pr >> (i + 1)) & 1u) {
        #pragma unroll
        for (int j = 0; j < NT; ++j) {
            if (j != i && ((pr >> (j + 1)) & 1u)) {
                float d2 = 0.f;
                #pragma unroll
                for (int cc = 0; cc < NC; ++cc) {
                    const float d = means[b][i][cc] - means[b][j][cc];
                    d2 += d * d;
                }
                const float dist = sqrtf(d2 + 1e-12f);
                const float r = fmaxf(LGG - dist, 0.f);
                loss += logf(r * r + 1.f);
                nv += 1.f;
            }
        }
    }
    #pragma unroll
    for (int o = 8; o; o >>= 1) { loss += __shfl_xor(loss, o); nv += __shfl_xor(nv, o); }
    if (i == 0) {
        const float v = (__popc(pr) >= 2) ? 1.f : 0.f;
        sl[b] = v * (loss / fmaxf(nv, 1.f));
        sn[b] = v;
    }
    __syncthreads();
    if (tid == 0) {
        float tl = 0.f, tv = 0.f;
        for (int bb = 0; bb < NB; ++bb) { tl += sl[bb]; tv += sn[bb]; }
        out[0] = (tv > 0.f) ? tl / tv : 0.f;
    }
}

extern "C" void kernel_launch(void* const* d_in, const int* in_sizes, int n_in,
                              void* d_out, int out_size, void* d_ws, size_t ws_size,
                              hipStream_t stream) {
    const int*   gk   = (const int*)d_in[0];
    const int*   mask = (const int*)d_in[1];
    const float* sim  = (const float*)d_in[2];
    float* out   = (float*)d_out;
    float* g_acc = (float*)d_ws;      // NB*160 floats

    init_ws<<<1, 256, 0, stream>>>(g_acc);
    accum<<<BLOCKS, THREADS, 0, stream>>>(gk, mask, sim, g_acc);
    finalize<<<1, 256, 0, stream>>>(g_acc, out);
}